// Round 18
// baseline (122.221 us; speedup 1.0000x reference)
//
#include <hip/hip_runtime.h>

#define NA 16
#define DD 513
#define ALPHA 0.1f
#define EPSV 1e-7f
#define GRID 768          // 3 blocks/CU exactly resident
#define NTILES 16384      // 131072 rows / 8
#define TW (GRID * 4)     // total waves = 3072; 5-6 tiles per wave

typedef __fp16 h2v __attribute__((ext_vector_type(2)));
typedef __fp16 f16x8 __attribute__((ext_vector_type(8)));
typedef float f32x4 __attribute__((ext_vector_type(4)));
typedef float f32x4u __attribute__((ext_vector_type(4), aligned(4)));
typedef unsigned int u32;

union H2U { h2v h; u32 u; };
union FU  { float f; u32 u; int i; };
union FRAG { u32 w[4]; f16x8 v; };
union U4   { uint4 v; u32 w[4]; };

static __device__ __forceinline__ u32 pkrtz(float lo, float hi) {
    H2U t; t.h = __builtin_amdgcn_cvt_pkrtz(lo, hi); return t.u;
}
static __device__ __forceinline__ h2v asH2(u32 w) { H2U t; t.u = w; return t.h; }

// 4-byte-aligned 16B vector (rows are only 4B aligned)
struct __attribute__((packed, aligned(4))) F4 { float x, y, z, w; };

// Frame (R13-verified): row-frame = 64 uint4 chunks; chunk u holds f16 of
// elements {4u..4u+3} and {256+4u..256+4u+3}; stored at frame[row][u^(row&7)].
// Conflict-free for stage-write / MFMA read / store-read / y-gather; A and B
// use the SAME enumeration so the MFMA k-dot is a consistent permutation.

__global__ __launch_bounds__(256, 3)
void hfield_kernel(const float* __restrict__ x,
                   const float* __restrict__ anc,
                   float* __restrict__ out) {
    __shared__ uint4 bframe[NA * 64];       // anchors, 16 KB (block-wide)
    __shared__ uint4 xframe[4][8 * 64];     // x tile, 8 KB per wave

    const int tid = threadIdx.x, lane = tid & 63, wid = tid >> 6;
    const int col = lane & 15, g = lane >> 4;

    const int gw = blockIdx.x * 4 + wid;    // global wave id = first tile
    uint4* xf = xframe[wid];

    // ---- issue tile-gw load burst FIRST: 16 dwordx4 in flight ----
    F4 nvA[8], nvB[8];
    {
        const float* p0 = x + (size_t)gw * 8 * DD;
#pragma unroll
        for (int r = 0; r < 8; ++r) {
            const float* p = p0 + (size_t)r * DD + 1 + 4 * lane;
            nvA[r] = *(const F4*)p;
            nvB[r] = *(const F4*)(p + 256);
        }
    }
    __builtin_amdgcn_sched_barrier(0);

    // ---- stage anchors into bframe ----
#pragma unroll
    for (int m = 0; m < 4; ++m) {
        const int i = m * 256 + tid;            // 0..1023
        const int a = i >> 6, u = i & 63;
        const float* p = anc + a * DD + 1 + 4 * u;
        const float* q = p + 256;
        uint4 w;
        w.x = pkrtz(p[0], p[1]);
        w.y = pkrtz(p[2], p[3]);
        w.z = pkrtz(q[0], q[1]);
        w.w = pkrtz(q[2], q[3]);
        bframe[a * 64 + (u ^ (a & 7))] = w;
    }

    // ---- af0 for anchor `col` (exact f32) ----
    float af0c;
    {
        const float* p = anc + col * DD + 1 + g * 128;
        float s = 0.f;
#pragma unroll 16
        for (int i = 0; i < 128; ++i) s = fmaf(p[i], p[i], s);
        s += __shfl_xor(s, 16);
        s += __shfl_xor(s, 32);
        af0c = sqrtf(1.0f + s);
    }
    __syncthreads();

    const float thmin = 1.0f + 1e-7f;

    // ---- grid-stride over 8-row tiles ----
#pragma unroll 1
    for (int t = gw; t < NTILES; t += TW) {
        const float* xt = x + (size_t)t * 8 * DD;

        // ---- drain regs -> xframe (f16 chunks, swizzled) ----
#pragma unroll
        for (int r = 0; r < 8; ++r) {
            uint4 w;
            w.x = pkrtz(nvA[r].x, nvA[r].y);
            w.y = pkrtz(nvA[r].z, nvA[r].w);
            w.z = pkrtz(nvB[r].x, nvB[r].y);
            w.w = pkrtz(nvB[r].z, nvB[r].w);
            xf[r * 64 + (lane ^ (r & 7))] = w;
        }

        // ---- regs free: issue NEXT tile's burst (hides under MFMA+store) ----
        if (t + TW < NTILES) {
            const float* nb = x + (size_t)(t + TW) * 8 * DD;
#pragma unroll
            for (int r = 0; r < 8; ++r) {
                const float* p = nb + (size_t)r * DD + 1 + 4 * lane;
                nvA[r] = *(const F4*)p;
                nvB[r] = *(const F4*)(p + 256);
            }
            __builtin_amdgcn_sched_barrier(0);
        }

        // x0 for this lane-group's rows (rows 8..15 duplicate 0..7; L1-hot)
        float x0r[4];
#pragma unroll
        for (int r4 = 0; r4 < 4; ++r4)
            x0r[r4] = xt[(size_t)((4 * g + r4) & 7) * DD];

        // ---- MFMA: S[row][anchor], 8 real rows (x2 dup) x 16 anchors, K=512 ----
        f32x4 acc = {0.f, 0.f, 0.f, 0.f};
#pragma unroll
        for (int kt = 0; kt < 16; ++kt) {
            const int u = 4 * kt + g;
            FRAG A, B;
            U4 ax, bx;
            ax.v = xf[(col & 7) * 64 + (u ^ (col & 7))];
            bx.v = bframe[col * 64 + (u ^ (col & 7))];
            A.w[0] = ax.w[0]; A.w[1] = ax.w[1]; A.w[2] = ax.w[2]; A.w[3] = ax.w[3];
            B.w[0] = bx.w[0]; B.w[1] = bx.w[1]; B.w[2] = bx.w[2]; B.w[3] = bx.w[3];
            acc = __builtin_amdgcn_mfma_f32_16x16x32_f16(A.v, B.v, acc, 0, 0, 0);
        }

        // ---- theta, argmin, epilogue: 4 chains per lane ----
        float c1r[4], c2r[4], o0r[4];
        int bir[4];
#pragma unroll
        for (int r4 = 0; r4 < 4; ++r4) {
            const float th = fmaxf(fmaf(x0r[r4], af0c, -acc[r4]), thmin);
            FU u; u.f = th;
            u32 key = (u.u & 0xFFFFFFF0u) | (u32)col;
#pragma unroll
            for (int m = 1; m <= 8; m <<= 1) {
                const u32 o = (u32)__shfl_xor((int)key, m);
                key = o < key ? o : key;
            }
            const int bi  = (int)(key & 15u);
            const int src = (lane & 48) | bi;
            const float thw = __shfl(th, src);     // exact winner theta
            const float y0  = __shfl(af0c, src);   // winner af0

            const float s2 = thw * thw - 1.0f;
            const float rr = sqrtf(s2);
            const float ac = __logf(thw + rr);     // arccosh
            const float cf = ac / rr;
            const float vn = sqrtf(fmaxf(ALPHA * ALPHA * ac * ac, EPSV));
            const float e  = __expf(vn);
            const float ei = 1.0f / e;
            const float ch = 0.5f * (e + ei);
            const float sh = 0.5f * (e - ei);
            const float c2 = ALPHA * cf * (sh / vn);
            const float c1 = fmaf(-c2, thw, ch);

            c1r[r4] = c1;
            c2r[r4] = c2;
            o0r[r4] = fmaf(c2, y0, c1 * x0r[r4]);
            bir[r4] = bi;
        }

        // ---- store: 8 rows, two contiguous dwordx4 streams per row ----
        // Regular (cached) stores: complete at L2 (~200cy ack) instead of the
        // HBM write queue -> vmcnt drains at the loop top stop stalling on
        // last tile's write acks; L2 smooths the write bursts.
#pragma unroll
        for (int r = 0; r < 8; ++r) {
            const int src = (r >> 2) * 16;        // producer lane-group
            const float c1 = __shfl(c1r[r & 3], src);
            const float c2 = __shfl(c2r[r & 3], src);
            const float o0 = __shfl(o0r[r & 3], src);
            const int   bi = __builtin_amdgcn_readfirstlane(__shfl(bir[r & 3], src));

            U4 X, Y;
            X.v = xf[r * 64 + (lane ^ (r & 7))];
            Y.v = bframe[bi * 64 + (lane ^ (bi & 7))];

            f32x4u s0, s1;
#pragma unroll
            for (int q = 0; q < 2; ++q) {
                const h2v hx = asH2(X.w[q]);
                const h2v hy = asH2(Y.w[q]);
                s0[2 * q]     = fmaf(c2, (float)hy.x, c1 * (float)hx.x);
                s0[2 * q + 1] = fmaf(c2, (float)hy.y, c1 * (float)hx.y);
            }
#pragma unroll
            for (int q = 0; q < 2; ++q) {
                const h2v hx = asH2(X.w[2 + q]);
                const h2v hy = asH2(Y.w[2 + q]);
                s1[2 * q]     = fmaf(c2, (float)hy.x, c1 * (float)hx.x);
                s1[2 * q + 1] = fmaf(c2, (float)hy.y, c1 * (float)hx.y);
            }
            float* op = out + (size_t)(t * 8 + r) * DD;
            *(f32x4u*)(op + 1 + 4 * lane) = s0;
            *(f32x4u*)(op + 257 + 4 * lane) = s1;
            if (lane == 0) op[0] = o0;
        }
    }
}

extern "C" void kernel_launch(void* const* d_in, const int* in_sizes, int n_in,
                              void* d_out, int out_size, void* d_ws, size_t ws_size,
                              hipStream_t stream) {
    const float* x   = (const float*)d_in[0];
    const float* anc = (const float*)d_in[1];
    float* out       = (float*)d_out;
    hipLaunchKernelGGL(hfield_kernel, dim3(GRID), dim3(256), 0, stream, x, anc, out);
}

// Round 19
// 100.266 us; speedup vs baseline: 1.2190x; 1.2190x over previous
//
#include <hip/hip_runtime.h>

#define NA 16
#define DD 513
#define ALPHA 0.1f
#define EPSV 1e-7f
#define GRID 768          // 3 blocks/CU exactly resident
#define NTILES 16384      // 131072 rows / 8
#define TW (GRID * 4)     // total waves = 3072; 5-6 tiles per wave

typedef __fp16 h2v __attribute__((ext_vector_type(2)));
typedef __fp16 f16x8 __attribute__((ext_vector_type(8)));
typedef float f32x4 __attribute__((ext_vector_type(4)));
typedef float f32x4u __attribute__((ext_vector_type(4), aligned(4)));
typedef unsigned int u32;

union H2U { h2v h; u32 u; };
union FU  { float f; u32 u; int i; };
union FRAG { u32 w[4]; f16x8 v; };
union U4   { uint4 v; u32 w[4]; };

static __device__ __forceinline__ u32 pkrtz(float lo, float hi) {
    H2U t; t.h = __builtin_amdgcn_cvt_pkrtz(lo, hi); return t.u;
}
static __device__ __forceinline__ h2v asH2(u32 w) { H2U t; t.u = w; return t.h; }

// 4-byte-aligned 16B vector (rows are only 4B aligned)
struct __attribute__((packed, aligned(4))) F4 { float x, y, z, w; };

// Frame (R13-verified): row-frame = 64 uint4 chunks; chunk u holds f16 of
// elements {4u..4u+3} and {256+4u..256+4u+3}; stored at frame[row][u^(row&7)].
// Conflict-free for stage-write / MFMA read / store-read / y-gather; A and B
// use the SAME enumeration so the MFMA k-dot is a consistent permutation.

__global__ __launch_bounds__(256, 3)
void hfield_kernel(const float* __restrict__ x,
                   const float* __restrict__ anc,
                   float* __restrict__ out) {
    __shared__ uint4 bframe[NA * 64];       // anchors, 16 KB (block-wide)
    __shared__ uint4 xframe[4][8 * 64];     // x tile, 8 KB per wave

    const int tid = threadIdx.x, lane = tid & 63, wid = tid >> 6;
    const int col = lane & 15, g = lane >> 4;

    const int gw = blockIdx.x * 4 + wid;    // global wave id = first tile
    uint4* xf = xframe[wid];

    // rows this lane's epilogue chains own (duplicated MFMA rows: &7)
    int myrow[4];
#pragma unroll
    for (int r4 = 0; r4 < 4; ++r4) myrow[r4] = (4 * g + r4) & 7;

    // ---- issue tile-gw load burst FIRST: 16 dwordx4 + 4 x0 dwords in flight ----
    F4 nvA[8], nvB[8];
    float nx0[4];
    {
        const float* p0 = x + (size_t)gw * 8 * DD;
#pragma unroll
        for (int r = 0; r < 8; ++r) {
            const float* p = p0 + (size_t)r * DD + 1 + 4 * lane;
            nvA[r] = *(const F4*)p;
            nvB[r] = *(const F4*)(p + 256);
        }
#pragma unroll
        for (int r4 = 0; r4 < 4; ++r4)
            nx0[r4] = p0[(size_t)myrow[r4] * DD];
    }
    __builtin_amdgcn_sched_barrier(0);

    // ---- stage anchors into bframe ----
#pragma unroll
    for (int m = 0; m < 4; ++m) {
        const int i = m * 256 + tid;            // 0..1023
        const int a = i >> 6, u = i & 63;
        const float* p = anc + a * DD + 1 + 4 * u;
        const float* q = p + 256;
        uint4 w;
        w.x = pkrtz(p[0], p[1]);
        w.y = pkrtz(p[2], p[3]);
        w.z = pkrtz(q[0], q[1]);
        w.w = pkrtz(q[2], q[3]);
        bframe[a * 64 + (u ^ (a & 7))] = w;
    }

    // ---- af0 for anchor `col` (exact f32) ----
    float af0c;
    {
        const float* p = anc + col * DD + 1 + g * 128;
        float s = 0.f;
#pragma unroll 16
        for (int i = 0; i < 128; ++i) s = fmaf(p[i], p[i], s);
        s += __shfl_xor(s, 16);
        s += __shfl_xor(s, 32);
        af0c = sqrtf(1.0f + s);
    }
    __syncthreads();

    const float thmin = 1.0f + 1e-7f;

    // ---- grid-stride over 8-row tiles ----
#pragma unroll 1
    for (int t = gw; t < NTILES; t += TW) {
        // ---- drain regs -> xframe (f16 chunks, swizzled) ----
#pragma unroll
        for (int r = 0; r < 8; ++r) {
            uint4 w;
            w.x = pkrtz(nvA[r].x, nvA[r].y);
            w.y = pkrtz(nvA[r].z, nvA[r].w);
            w.z = pkrtz(nvB[r].x, nvB[r].y);
            w.w = pkrtz(nvB[r].z, nvB[r].w);
            xf[r * 64 + (lane ^ (r & 7))] = w;
        }

        // x0 for this tile arrived with the burst (issued one period ago)
        float x0r[4];
#pragma unroll
        for (int r4 = 0; r4 < 4; ++r4) x0r[r4] = nx0[r4];

        // ---- regs free: issue NEXT tile's burst (hides under MFMA+store) ----
        if (t + TW < NTILES) {
            const float* nb = x + (size_t)(t + TW) * 8 * DD;
#pragma unroll
            for (int r = 0; r < 8; ++r) {
                const float* p = nb + (size_t)r * DD + 1 + 4 * lane;
                nvA[r] = *(const F4*)p;
                nvB[r] = *(const F4*)(p + 256);
            }
#pragma unroll
            for (int r4 = 0; r4 < 4; ++r4)
                nx0[r4] = nb[(size_t)myrow[r4] * DD];
            __builtin_amdgcn_sched_barrier(0);
        }

        // ---- MFMA: S[row][anchor], 8 real rows (x2 dup) x 16 anchors, K=512 ----
        f32x4 acc = {0.f, 0.f, 0.f, 0.f};
#pragma unroll
        for (int kt = 0; kt < 16; ++kt) {
            const int u = 4 * kt + g;
            FRAG A, B;
            U4 ax, bx;
            ax.v = xf[(col & 7) * 64 + (u ^ (col & 7))];
            bx.v = bframe[col * 64 + (u ^ (col & 7))];
            A.w[0] = ax.w[0]; A.w[1] = ax.w[1]; A.w[2] = ax.w[2]; A.w[3] = ax.w[3];
            B.w[0] = bx.w[0]; B.w[1] = bx.w[1]; B.w[2] = bx.w[2]; B.w[3] = bx.w[3];
            acc = __builtin_amdgcn_mfma_f32_16x16x32_f16(A.v, B.v, acc, 0, 0, 0);
        }

        // ---- theta, argmin, epilogue: 4 chains per lane ----
        float c1r[4], c2r[4], o0r[4];
        int bir[4];
#pragma unroll
        for (int r4 = 0; r4 < 4; ++r4) {
            const float th = fmaxf(fmaf(x0r[r4], af0c, -acc[r4]), thmin);
            FU u; u.f = th;
            u32 key = (u.u & 0xFFFFFFF0u) | (u32)col;
#pragma unroll
            for (int m = 1; m <= 8; m <<= 1) {
                const u32 o = (u32)__shfl_xor((int)key, m);
                key = o < key ? o : key;
            }
            const int bi  = (int)(key & 15u);
            const int src = (lane & 48) | bi;
            const float thw = __shfl(th, src);     // exact winner theta
            const float y0  = __shfl(af0c, src);   // winner af0

            const float s2 = thw * thw - 1.0f;
            const float rr = sqrtf(s2);
            const float ac = __logf(thw + rr);     // arccosh
            const float cf = ac / rr;
            const float vn = sqrtf(fmaxf(ALPHA * ALPHA * ac * ac, EPSV));
            const float e  = __expf(vn);
            const float ei = 1.0f / e;
            const float ch = 0.5f * (e + ei);
            const float sh = 0.5f * (e - ei);
            const float c2 = ALPHA * cf * (sh / vn);
            const float c1 = fmaf(-c2, thw, ch);

            c1r[r4] = c1;
            c2r[r4] = c2;
            o0r[r4] = fmaf(c2, y0, c1 * x0r[r4]);
            bir[r4] = bi;
        }

        // ---- store: 8 rows, two contiguous dwordx4 NT streams per row ----
#pragma unroll
        for (int r = 0; r < 8; ++r) {
            const int src = (r >> 2) * 16;        // producer lane-group
            const float c1 = __shfl(c1r[r & 3], src);
            const float c2 = __shfl(c2r[r & 3], src);
            const float o0 = __shfl(o0r[r & 3], src);
            const int   bi = __builtin_amdgcn_readfirstlane(__shfl(bir[r & 3], src));

            U4 X, Y;
            X.v = xf[r * 64 + (lane ^ (r & 7))];
            Y.v = bframe[bi * 64 + (lane ^ (bi & 7))];

            f32x4u s0, s1;
#pragma unroll
            for (int q = 0; q < 2; ++q) {
                const h2v hx = asH2(X.w[q]);
                const h2v hy = asH2(Y.w[q]);
                s0[2 * q]     = fmaf(c2, (float)hy.x, c1 * (float)hx.x);
                s0[2 * q + 1] = fmaf(c2, (float)hy.y, c1 * (float)hx.y);
            }
#pragma unroll
            for (int q = 0; q < 2; ++q) {
                const h2v hx = asH2(X.w[2 + q]);
                const h2v hy = asH2(Y.w[2 + q]);
                s1[2 * q]     = fmaf(c2, (float)hy.x, c1 * (float)hx.x);
                s1[2 * q + 1] = fmaf(c2, (float)hy.y, c1 * (float)hx.y);
            }
            float* op = out + (size_t)(t * 8 + r) * DD;
            __builtin_nontemporal_store(s0, (f32x4u*)(op + 1 + 4 * lane));
            __builtin_nontemporal_store(s1, (f32x4u*)(op + 257 + 4 * lane));
            if (lane == 0) __builtin_nontemporal_store(o0, op);
        }
    }
}

extern "C" void kernel_launch(void* const* d_in, const int* in_sizes, int n_in,
                              void* d_out, int out_size, void* d_ws, size_t ws_size,
                              hipStream_t stream) {
    const float* x   = (const float*)d_in[0];
    const float* anc = (const float*)d_in[1];
    float* out       = (float*)d_out;
    hipLaunchKernelGGL(hfield_kernel, dim3(GRID), dim3(256), 0, stream, x, anc, out);
}